// Round 4
// baseline (87.107 us; speedup 1.0000x reference)
//
#include <hip/hip_runtime.h>
#include <math.h>

#define KFEAT 32768
#define GRID_N 33              // 33x33 grid, step = 1/32 of domain
#define NPTS (GRID_N * GRID_N) // 1089
#define PTS_PER_BLOCK 8
#define PBLOCKS ((NPTS + PTS_PER_BLOCK - 1) / PTS_PER_BLOCK)  // 137
#define SPLITK 8
#define NBLOCKS (PBLOCKS * SPLITK)  // 1096
#define COUNTER_OFFSET 40960  // bytes into d_ws; Fpart needs 34848 bytes

// ---------------------------------------------------------------------------
// Morton helpers for the reference's interleaved quadrant order (base-4
// digits, MSB = depth 1): ix = even bits compacted, iy = odd bits compacted.
// ---------------------------------------------------------------------------
__device__ __forceinline__ int compact_bits(int v, int shift) {
  int r = (v >> shift) & 1;
  r |= ((v >> (shift + 2)) & 1) << 1;
  r |= ((v >> (shift + 4)) & 1) << 2;
  r |= ((v >> (shift + 6)) & 1) << 3;
  return r;
}

__device__ __forceinline__ float simpson_cell(const float* __restrict__ F,
                                              int d, int cell, float hx,
                                              float hy) {
  const int ix = compact_bits(cell, 0);
  const int iy = compact_bits(cell, 1);
  const int s = 5 - d;        // log2 of cell size in grid units
  const int h = 1 << (s - 1); // half-cell in grid units
  const int gx0 = ix << s, gx1 = gx0 + h, gx2 = gx0 + 2 * h;
  const int gy0 = iy << s, gy1 = gy0 + h, gy2 = gy0 + 2 * h;
  // point order: 0:(xl,yl) 1:(mx,yl) 2:(xr,yl) 3:(xl,my) 4:(xr,my)
  //              5:(xl,yr) 6:(mx,yr) 7:(xr,yr)   (center skipped, coeff 0)
  const float f0 = F[gy0 * GRID_N + gx0];
  const float f1 = F[gy0 * GRID_N + gx1];
  const float f2 = F[gy0 * GRID_N + gx2];
  const float f3 = F[gy1 * GRID_N + gx0];
  const float f4 = F[gy1 * GRID_N + gx2];
  const float f5 = F[gy2 * GRID_N + gx0];
  const float f6 = F[gy2 * GRID_N + gx1];
  const float f7 = F[gy2 * GRID_N + gx2];
  return hx * hy * (1.0f / 12.0f) *
         (-(f0 + f2 + f5 + f7) + 4.0f * (f1 + f3 + f4 + f6));
}

// ---------------------------------------------------------------------------
// Fused kernel, last-block-done ticket instead of cooperative grid.sync().
// Phase 1 (all blocks): split-K partial sums of
//   f(x,y) = sum_k w_k * cos(ax_k x + ay_k y + phi_k)
// on the 33x33 grid -> Fpart[split][point].
// Release: __syncthreads (drains vmem) + __threadfence, then ticket atomic.
// Phase 2 (last-finishing block only): acquire fence, sum partials, Simpson
// cells at depths 0..4, adaptive tree combine (reproducing the reference's
// q3-whole bug, the eps/4^d schedule, and the depth-3 truncation).
// ---------------------------------------------------------------------------
__global__ __launch_bounds__(256) void fused_kernel(
    const float4* __restrict__ w4, const float4* __restrict__ ax4,
    const float4* __restrict__ ay4, const float4* __restrict__ phi4,
    const float* __restrict__ xa_p, const float* __restrict__ xb_p,
    const float* __restrict__ ya_p, const float* __restrict__ yb_p,
    const float* __restrict__ eps_p, float* __restrict__ Fpart,
    int* __restrict__ counter, float* __restrict__ out) {
  const int tid = threadIdx.x;
  const int split = blockIdx.x & (SPLITK - 1);
  const int pblk = blockIdx.x >> 3;  // SPLITK == 8
  const float xa = xa_p[0], xb = xb_p[0];
  const float ya = ya_p[0], yb = yb_p[0];
  const float sx = (xb - xa) * (1.0f / 32.0f);
  const float sy = (yb - ya) * (1.0f / 32.0f);

  // ---------------- phase 1: eval partials ----------------
  {
    const int p0 = pblk * PTS_PER_BLOCK;
    float x[PTS_PER_BLOCK], y[PTS_PER_BLOCK];
#pragma unroll
    for (int j = 0; j < PTS_PER_BLOCK; ++j) {
      int p = min(p0 + j, NPTS - 1);  // clamp; duplicate work, write guarded
      int gx = p % GRID_N;
      int gy = p / GRID_N;
      x[j] = fmaf((float)gx, sx, xa);
      y[j] = fmaf((float)gy, sy, ya);
    }

    float acc[PTS_PER_BLOCK];
#pragma unroll
    for (int j = 0; j < PTS_PER_BLOCK; ++j) acc[j] = 0.0f;

    const int k4_per_split = (KFEAT / 4) / SPLITK;  // 1024
    const int base = split * k4_per_split;
    for (int i = tid; i < k4_per_split; i += 256) {
      const float4 A = ax4[base + i];
      const float4 B = ay4[base + i];
      const float4 P = phi4[base + i];
      const float4 W = w4[base + i];
#pragma unroll
      for (int j = 0; j < PTS_PER_BLOCK; ++j) {
        float t0 = fmaf(A.x, x[j], fmaf(B.x, y[j], P.x));
        float t1 = fmaf(A.y, x[j], fmaf(B.y, y[j], P.y));
        float t2 = fmaf(A.z, x[j], fmaf(B.z, y[j], P.z));
        float t3 = fmaf(A.w, x[j], fmaf(B.w, y[j], P.w));
        float s = fmaf(W.x, __cosf(t0), fmaf(W.y, __cosf(t1),
                  fmaf(W.z, __cosf(t2), W.w * __cosf(t3))));
        acc[j] += s;
      }
    }

    // Reduce each accumulator across the 256-thread block.
    __shared__ float red[4][PTS_PER_BLOCK];  // [wave][point]
#pragma unroll
    for (int j = 0; j < PTS_PER_BLOCK; ++j) {
      float v = acc[j];
#pragma unroll
      for (int off = 32; off > 0; off >>= 1) v += __shfl_down(v, off, 64);
      if ((tid & 63) == 0) red[tid >> 6][j] = v;
    }
    __syncthreads();
    if (tid < PTS_PER_BLOCK) {
      const int j = tid;
      float v = red[0][j] + red[1][j] + red[2][j] + red[3][j];
      int p = p0 + j;
      if (p < NPTS) Fpart[split * NPTS + p] = v;
    }
  }

  // ---------------- ticket: last finishing block combines ----------------
  __syncthreads();     // drains our global stores (vmcnt) before the fence
  __threadfence();     // device-scope release
  __shared__ int is_last;
  if (tid == 0) {
    int old = atomicAdd(counter, 1);
    is_last = (old == NBLOCKS - 1) ? 1 : 0;
  }
  __syncthreads();
  if (!is_last) return;
  __threadfence();     // device-scope acquire (invalidate stale cache)

  // ---------------- phase 2: combine ----------------
  {
    __shared__ float Fs[NPTS];
    __shared__ float S4[256], S3[64], S2[16], S1[4], S0[1];
    __shared__ float val3[64], val2[16], val1[4];
    const int t = tid;
    const float eps = *eps_p;
    const float HX = fabsf(xb - xa), HY = fabsf(yb - ya);

    for (int p = t; p < NPTS; p += 256) {
      float v = 0.0f;
#pragma unroll
      for (int s = 0; s < SPLITK; ++s) v += Fpart[s * NPTS + p];
      Fs[p] = v;
    }
    __syncthreads();

    // Simpson estimates at every depth
    S4[t] = simpson_cell(Fs, 4, t, HX * 0.0625f, HY * 0.0625f);
    if (t < 64) {
      S3[t] = simpson_cell(Fs, 3, t, HX * 0.125f, HY * 0.125f);
    } else if (t < 80) {
      S2[t - 64] = simpson_cell(Fs, 2, t - 64, HX * 0.25f, HY * 0.25f);
    } else if (t < 84) {
      S1[t - 80] = simpson_cell(Fs, 1, t - 80, HX * 0.5f, HY * 0.5f);
    } else if (t == 84) {
      S0[0] = simpson_cell(Fs, 0, 0, HX, HY);
    }
    __syncthreads();

    // d = 3 (MAX_DEPTH-1): truncate -> corrected unconditionally
    if (t < 64) {
      float sumq =
          ((S4[4 * t] + S4[4 * t + 1]) + S4[4 * t + 2]) + S4[4 * t + 3];
      // reference bug reproduced: quadrant 3 'whole' is quadrant 0's S
      float whole = ((t & 3) == 3) ? S3[t & ~3] : S3[t];
      float delta = sumq - whole;
      val3[t] = sumq + delta * (1.0f / 15.0f);
    }
    __syncthreads();

    // d = 2
    if (t < 16) {
      float sumq =
          ((S3[4 * t] + S3[4 * t + 1]) + S3[4 * t + 2]) + S3[4 * t + 3];
      float whole = ((t & 3) == 3) ? S2[t & ~3] : S2[t];
      float delta = sumq - whole;
      float corrected = sumq + delta * (1.0f / 15.0f);
      float child =
          ((val3[4 * t] + val3[4 * t + 1]) + val3[4 * t + 2]) + val3[4 * t + 3];
      float eps_d = eps * (1.0f / 16.0f);  // eps / 4^2
      val2[t] = (fabsf(delta) <= 15.0f * eps_d) ? corrected : child;
    }
    __syncthreads();

    // d = 1
    if (t < 4) {
      float sumq =
          ((S2[4 * t] + S2[4 * t + 1]) + S2[4 * t + 2]) + S2[4 * t + 3];
      float whole = ((t & 3) == 3) ? S1[t & ~3] : S1[t];
      float delta = sumq - whole;
      float corrected = sumq + delta * (1.0f / 15.0f);
      float child =
          ((val2[4 * t] + val2[4 * t + 1]) + val2[4 * t + 2]) + val2[4 * t + 3];
      float eps_d = eps * 0.25f;  // eps / 4^1
      val1[t] = (fabsf(delta) <= 15.0f * eps_d) ? corrected : child;
    }
    __syncthreads();

    // d = 0
    if (t == 0) {
      float sumq = ((S1[0] + S1[1]) + S1[2]) + S1[3];
      float delta = sumq - S0[0];
      float corrected = sumq + delta * (1.0f / 15.0f);
      float child = ((val1[0] + val1[1]) + val1[2]) + val1[3];
      out[0] = (fabsf(delta) <= 15.0f * eps) ? corrected : child;
    }
  }
}

extern "C" void kernel_launch(void* const* d_in, const int* in_sizes, int n_in,
                              void* d_out, int out_size, void* d_ws,
                              size_t ws_size, hipStream_t stream) {
  // input order: xa, xb, ya, yb, eps, w, ax, ay, phi
  const float* xa = (const float*)d_in[0];
  const float* xb = (const float*)d_in[1];
  const float* ya = (const float*)d_in[2];
  const float* yb = (const float*)d_in[3];
  const float* eps = (const float*)d_in[4];
  const float4* w4 = (const float4*)d_in[5];
  const float4* ax4 = (const float4*)d_in[6];
  const float4* ay4 = (const float4*)d_in[7];
  const float4* phi4 = (const float4*)d_in[8];
  float* out = (float*)d_out;
  float* Fpart = (float*)d_ws;  // SPLITK * NPTS floats (34848 B)
  int* counter = (int*)((char*)d_ws + COUNTER_OFFSET);

  // Re-zero the ticket counter every call (graph-captured as a memset node,
  // so it also re-zeros on every timed replay).
  hipMemsetAsync(counter, 0, sizeof(int), stream);

  fused_kernel<<<NBLOCKS, 256, 0, stream>>>(w4, ax4, ay4, phi4, xa, xb, ya, yb,
                                            eps, Fpart, counter, out);
}

// Round 5
// 31.142 us; speedup vs baseline: 2.7971x; 2.7971x over previous
//
#include <hip/hip_runtime.h>
#include <math.h>

#define KFEAT 32768
#define GRID_N 33              // 33x33 grid, step = 1/32 of domain
#define NPTS (GRID_N * GRID_N) // 1089
#define PTS_PER_BLOCK 8
#define PBLOCKS ((NPTS + PTS_PER_BLOCK - 1) / PTS_PER_BLOCK)  // 137
#define SPLITK 8
#define NBLOCKS (PBLOCKS * SPLITK)  // 1096
#define COUNTER_OFFSET 40960  // bytes into d_ws; Fpart needs 34848 bytes

// ---------------------------------------------------------------------------
// Morton helpers for the reference's interleaved quadrant order (base-4
// digits, MSB = depth 1): ix = even bits compacted, iy = odd bits compacted.
// ---------------------------------------------------------------------------
__device__ __forceinline__ int compact_bits(int v, int shift) {
  int r = (v >> shift) & 1;
  r |= ((v >> (shift + 2)) & 1) << 1;
  r |= ((v >> (shift + 4)) & 1) << 2;
  r |= ((v >> (shift + 6)) & 1) << 3;
  return r;
}

__device__ __forceinline__ float simpson_cell(const float* __restrict__ F,
                                              int d, int cell, float hx,
                                              float hy) {
  const int ix = compact_bits(cell, 0);
  const int iy = compact_bits(cell, 1);
  const int s = 5 - d;        // log2 of cell size in grid units
  const int h = 1 << (s - 1); // half-cell in grid units
  const int gx0 = ix << s, gx1 = gx0 + h, gx2 = gx0 + 2 * h;
  const int gy0 = iy << s, gy1 = gy0 + h, gy2 = gy0 + 2 * h;
  // point order: 0:(xl,yl) 1:(mx,yl) 2:(xr,yl) 3:(xl,my) 4:(xr,my)
  //              5:(xl,yr) 6:(mx,yr) 7:(xr,yr)   (center skipped, coeff 0)
  const float f0 = F[gy0 * GRID_N + gx0];
  const float f1 = F[gy0 * GRID_N + gx1];
  const float f2 = F[gy0 * GRID_N + gx2];
  const float f3 = F[gy1 * GRID_N + gx0];
  const float f4 = F[gy1 * GRID_N + gx2];
  const float f5 = F[gy2 * GRID_N + gx0];
  const float f6 = F[gy2 * GRID_N + gx1];
  const float f7 = F[gy2 * GRID_N + gx2];
  return hx * hy * (1.0f / 12.0f) *
         (-(f0 + f2 + f5 + f7) + 4.0f * (f1 + f3 + f4 + f6));
}

// ---------------------------------------------------------------------------
// Fused kernel, last-block-done ticket. Cross-XCD visibility is achieved
// WITHOUT any cache-flushing fences (__threadfence = buffer_wbl2 per block
// was the R4 85us regression):
//   - Fpart stores are agent-scope relaxed atomics (sc0 sc1 write-through,
//     device-visible at the coherence point when vmcnt retires).
//   - release = s_waitcnt vmcnt(0) in the storing wave, then a RELAXED
//     agent-scope fetch_add ticket.
//   - the winner (saw NBLOCKS-1) reads Fpart with agent-scope relaxed
//     atomic loads (bypass stale L1/L2) -- no buffer_inv needed.
// ---------------------------------------------------------------------------
__global__ __launch_bounds__(256) void fused_kernel(
    const float4* __restrict__ w4, const float4* __restrict__ ax4,
    const float4* __restrict__ ay4, const float4* __restrict__ phi4,
    const float* __restrict__ xa_p, const float* __restrict__ xb_p,
    const float* __restrict__ ya_p, const float* __restrict__ yb_p,
    const float* __restrict__ eps_p, float* __restrict__ Fpart,
    int* __restrict__ counter, float* __restrict__ out) {
  const int tid = threadIdx.x;
  const int split = blockIdx.x & (SPLITK - 1);
  const int pblk = blockIdx.x >> 3;  // SPLITK == 8
  const float xa = xa_p[0], xb = xb_p[0];
  const float ya = ya_p[0], yb = yb_p[0];
  const float sx = (xb - xa) * (1.0f / 32.0f);
  const float sy = (yb - ya) * (1.0f / 32.0f);

  // ---------------- phase 1: eval partials ----------------
  {
    const int p0 = pblk * PTS_PER_BLOCK;
    float x[PTS_PER_BLOCK], y[PTS_PER_BLOCK];
#pragma unroll
    for (int j = 0; j < PTS_PER_BLOCK; ++j) {
      int p = min(p0 + j, NPTS - 1);  // clamp; duplicate work, write guarded
      int gx = p % GRID_N;
      int gy = p / GRID_N;
      x[j] = fmaf((float)gx, sx, xa);
      y[j] = fmaf((float)gy, sy, ya);
    }

    float acc[PTS_PER_BLOCK];
#pragma unroll
    for (int j = 0; j < PTS_PER_BLOCK; ++j) acc[j] = 0.0f;

    const int k4_per_split = (KFEAT / 4) / SPLITK;  // 1024
    const int base = split * k4_per_split;
    for (int i = tid; i < k4_per_split; i += 256) {
      const float4 A = ax4[base + i];
      const float4 B = ay4[base + i];
      const float4 P = phi4[base + i];
      const float4 W = w4[base + i];
#pragma unroll
      for (int j = 0; j < PTS_PER_BLOCK; ++j) {
        float t0 = fmaf(A.x, x[j], fmaf(B.x, y[j], P.x));
        float t1 = fmaf(A.y, x[j], fmaf(B.y, y[j], P.y));
        float t2 = fmaf(A.z, x[j], fmaf(B.z, y[j], P.z));
        float t3 = fmaf(A.w, x[j], fmaf(B.w, y[j], P.w));
        float s = fmaf(W.x, __cosf(t0), fmaf(W.y, __cosf(t1),
                  fmaf(W.z, __cosf(t2), W.w * __cosf(t3))));
        acc[j] += s;
      }
    }

    // Reduce each accumulator across the 256-thread block.
    __shared__ float red[4][PTS_PER_BLOCK];  // [wave][point]
#pragma unroll
    for (int j = 0; j < PTS_PER_BLOCK; ++j) {
      float v = acc[j];
#pragma unroll
      for (int off = 32; off > 0; off >>= 1) v += __shfl_down(v, off, 64);
      if ((tid & 63) == 0) red[tid >> 6][j] = v;
    }
    __syncthreads();
    if (tid < PTS_PER_BLOCK) {
      const int j = tid;
      float v = red[0][j] + red[1][j] + red[2][j] + red[3][j];
      int p = p0 + j;
      if (p < NPTS) {
        // agent-scope write-through store: device-visible once vmcnt retires
        __hip_atomic_store(&Fpart[split * NPTS + p], v, __ATOMIC_RELAXED,
                           __HIP_MEMORY_SCOPE_AGENT);
      }
    }
  }

  // ---------------- ticket: last finishing block combines ----------------
  // Stores above and this ticket are both in wave 0 -> per-wave vmcnt(0)
  // is a sufficient release for the sc1 write-through stores. No wbl2/inv.
  __shared__ int is_last;
  if (tid == 0) {
    asm volatile("s_waitcnt vmcnt(0)" ::: "memory");
    int old = __hip_atomic_fetch_add(counter, 1, __ATOMIC_RELAXED,
                                     __HIP_MEMORY_SCOPE_AGENT);
    is_last = (old == NBLOCKS - 1) ? 1 : 0;
  }
  __syncthreads();
  if (!is_last) return;

  // ---------------- phase 2: combine (winner block only) ----------------
  {
    __shared__ float Fs[NPTS];
    __shared__ float S4[256], S3[64], S2[16], S1[4], S0[1];
    __shared__ float val3[64], val2[16], val1[4];
    const int t = tid;
    const float eps = *eps_p;
    const float HX = fabsf(xb - xa), HY = fabsf(yb - ya);

    for (int p = t; p < NPTS; p += 256) {
      float v = 0.0f;
#pragma unroll
      for (int s = 0; s < SPLITK; ++s) {
        // agent-scope load: bypasses (possibly stale) L1/L2
        v += __hip_atomic_load(&Fpart[s * NPTS + p], __ATOMIC_RELAXED,
                               __HIP_MEMORY_SCOPE_AGENT);
      }
      Fs[p] = v;
    }
    __syncthreads();

    // Simpson estimates at every depth
    S4[t] = simpson_cell(Fs, 4, t, HX * 0.0625f, HY * 0.0625f);
    if (t < 64) {
      S3[t] = simpson_cell(Fs, 3, t, HX * 0.125f, HY * 0.125f);
    } else if (t < 80) {
      S2[t - 64] = simpson_cell(Fs, 2, t - 64, HX * 0.25f, HY * 0.25f);
    } else if (t < 84) {
      S1[t - 80] = simpson_cell(Fs, 1, t - 80, HX * 0.5f, HY * 0.5f);
    } else if (t == 84) {
      S0[0] = simpson_cell(Fs, 0, 0, HX, HY);
    }
    __syncthreads();

    // d = 3 (MAX_DEPTH-1): truncate -> corrected unconditionally
    if (t < 64) {
      float sumq =
          ((S4[4 * t] + S4[4 * t + 1]) + S4[4 * t + 2]) + S4[4 * t + 3];
      // reference bug reproduced: quadrant 3 'whole' is quadrant 0's S
      float whole = ((t & 3) == 3) ? S3[t & ~3] : S3[t];
      float delta = sumq - whole;
      val3[t] = sumq + delta * (1.0f / 15.0f);
    }
    __syncthreads();

    // d = 2
    if (t < 16) {
      float sumq =
          ((S3[4 * t] + S3[4 * t + 1]) + S3[4 * t + 2]) + S3[4 * t + 3];
      float whole = ((t & 3) == 3) ? S2[t & ~3] : S2[t];
      float delta = sumq - whole;
      float corrected = sumq + delta * (1.0f / 15.0f);
      float child =
          ((val3[4 * t] + val3[4 * t + 1]) + val3[4 * t + 2]) + val3[4 * t + 3];
      float eps_d = eps * (1.0f / 16.0f);  // eps / 4^2
      val2[t] = (fabsf(delta) <= 15.0f * eps_d) ? corrected : child;
    }
    __syncthreads();

    // d = 1
    if (t < 4) {
      float sumq =
          ((S2[4 * t] + S2[4 * t + 1]) + S2[4 * t + 2]) + S2[4 * t + 3];
      float whole = ((t & 3) == 3) ? S1[t & ~3] : S1[t];
      float delta = sumq - whole;
      float corrected = sumq + delta * (1.0f / 15.0f);
      float child =
          ((val2[4 * t] + val2[4 * t + 1]) + val2[4 * t + 2]) + val2[4 * t + 3];
      float eps_d = eps * 0.25f;  // eps / 4^1
      val1[t] = (fabsf(delta) <= 15.0f * eps_d) ? corrected : child;
    }
    __syncthreads();

    // d = 0
    if (t == 0) {
      float sumq = ((S1[0] + S1[1]) + S1[2]) + S1[3];
      float delta = sumq - S0[0];
      float corrected = sumq + delta * (1.0f / 15.0f);
      float child = ((val1[0] + val1[1]) + val1[2]) + val1[3];
      out[0] = (fabsf(delta) <= 15.0f * eps) ? corrected : child;
    }
  }
}

extern "C" void kernel_launch(void* const* d_in, const int* in_sizes, int n_in,
                              void* d_out, int out_size, void* d_ws,
                              size_t ws_size, hipStream_t stream) {
  // input order: xa, xb, ya, yb, eps, w, ax, ay, phi
  const float* xa = (const float*)d_in[0];
  const float* xb = (const float*)d_in[1];
  const float* ya = (const float*)d_in[2];
  const float* yb = (const float*)d_in[3];
  const float* eps = (const float*)d_in[4];
  const float4* w4 = (const float4*)d_in[5];
  const float4* ax4 = (const float4*)d_in[6];
  const float4* ay4 = (const float4*)d_in[7];
  const float4* phi4 = (const float4*)d_in[8];
  float* out = (float*)d_out;
  float* Fpart = (float*)d_ws;  // SPLITK * NPTS floats (34848 B)
  int* counter = (int*)((char*)d_ws + COUNTER_OFFSET);

  // Re-zero the ticket counter every call (graph-captured as a memset node,
  // so it also re-zeros on every timed replay).
  hipMemsetAsync(counter, 0, sizeof(int), stream);

  fused_kernel<<<NBLOCKS, 256, 0, stream>>>(w4, ax4, ay4, phi4, xa, xb, ya, yb,
                                            eps, Fpart, counter, out);
}

// Round 6
// 18.283 us; speedup vs baseline: 4.7644x; 1.7034x over previous
//
#include <hip/hip_runtime.h>
#include <math.h>

#define KFEAT 32768
#define GRID_N 33              // 33x33 grid, step = 1/32 of domain
#define NPTS (GRID_N * GRID_N) // 1089
#define PTS_PER_BLOCK 8
#define PBLOCKS ((NPTS + PTS_PER_BLOCK - 1) / PTS_PER_BLOCK)  // 137
#define SPLITK 8
#define FP_STRIDE 1092         // NPTS padded to multiple of 4 (16B groups)
#define FP_GROUPS (FP_STRIDE / 4)  // 273 float4 groups per split row

// ---------------------------------------------------------------------------
// Kernel 1: evaluate f on the 33x33 grid, split-K partials.
// f(x,y) = sum_k w_k * cos(ax_k x + ay_k y + phi_k)
// grid = (137 point-blocks, 8 K-splits); each thread owns exactly 4 float4
// k-groups (16 k's), fully unrolled with ALL 16 loads hoisted up front so
// 16 loads/thread are in flight (R2 was latency-bound with ~1 in flight).
// ---------------------------------------------------------------------------
__global__ __launch_bounds__(256) void eval_grid_kernel(
    const float4* __restrict__ w4, const float4* __restrict__ ax4,
    const float4* __restrict__ ay4, const float4* __restrict__ phi4,
    const float* __restrict__ xa_p, const float* __restrict__ xb_p,
    const float* __restrict__ ya_p, const float* __restrict__ yb_p,
    float* __restrict__ Fpart) {
  const int tid = threadIdx.x;
  const int pblk = blockIdx.x;
  const int split = blockIdx.y;
  const float xa = xa_p[0], xb = xb_p[0];
  const float ya = ya_p[0], yb = yb_p[0];
  const float sx = (xb - xa) * (1.0f / 32.0f);
  const float sy = (yb - ya) * (1.0f / 32.0f);

  const int p0 = pblk * PTS_PER_BLOCK;
  float x[PTS_PER_BLOCK], y[PTS_PER_BLOCK];
#pragma unroll
  for (int j = 0; j < PTS_PER_BLOCK; ++j) {
    int p = min(p0 + j, NPTS - 1);  // clamp; duplicate work, write guarded
    int gx = p % GRID_N;
    int gy = p / GRID_N;
    x[j] = fmaf((float)gx, sx, xa);
    y[j] = fmaf((float)gy, sy, ya);
  }

  // ---- hoisted loads: 4 unrolled k-iterations x 4 arrays = 16 float4 ----
  const int base4 = split * ((KFEAT / 4) / SPLITK);  // 1024 float4 per split
  float4 A[4], B[4], P[4], W[4];
#pragma unroll
  for (int u = 0; u < 4; ++u) {
    const int idx = base4 + tid + 256 * u;
    A[u] = ax4[idx];
    B[u] = ay4[idx];
    P[u] = phi4[idx];
    W[u] = w4[idx];
  }

  float acc[PTS_PER_BLOCK];
#pragma unroll
  for (int j = 0; j < PTS_PER_BLOCK; ++j) acc[j] = 0.0f;

#pragma unroll
  for (int u = 0; u < 4; ++u) {
#pragma unroll
    for (int j = 0; j < PTS_PER_BLOCK; ++j) {
      float t0 = fmaf(A[u].x, x[j], fmaf(B[u].x, y[j], P[u].x));
      float t1 = fmaf(A[u].y, x[j], fmaf(B[u].y, y[j], P[u].y));
      float t2 = fmaf(A[u].z, x[j], fmaf(B[u].z, y[j], P[u].z));
      float t3 = fmaf(A[u].w, x[j], fmaf(B[u].w, y[j], P[u].w));
      float s = fmaf(W[u].x, __cosf(t0), fmaf(W[u].y, __cosf(t1),
                fmaf(W[u].z, __cosf(t2), W[u].w * __cosf(t3))));
      acc[j] += s;
    }
  }

  // Reduce each of the 8 accumulators across the 256-thread block.
  __shared__ float red[4][PTS_PER_BLOCK];  // [wave][point]
#pragma unroll
  for (int j = 0; j < PTS_PER_BLOCK; ++j) {
    float v = acc[j];
#pragma unroll
    for (int off = 32; off > 0; off >>= 1) v += __shfl_down(v, off, 64);
    if ((tid & 63) == 0) red[tid >> 6][j] = v;
  }
  __syncthreads();
  if (tid < PTS_PER_BLOCK) {
    const int j = tid;
    float v = red[0][j] + red[1][j] + red[2][j] + red[3][j];
    int p = p0 + j;
    if (p < NPTS) Fpart[split * FP_STRIDE + p] = v;
  }
}

// ---------------------------------------------------------------------------
// Kernel 2: sum split-K partials into LDS (vectorized: 273 threads x 8
// independent float4 loads, all in flight at once), then Simpson cells at
// depths 0..4 + adaptive tree combine. Cell index uses the reference's
// interleaved quadrant order (base-4 digits, MSB = depth 1): ix = even bits
// compacted, iy = odd bits compacted (Morton).
// ---------------------------------------------------------------------------
__device__ __forceinline__ int compact_bits(int v, int shift) {
  int r = (v >> shift) & 1;
  r |= ((v >> (shift + 2)) & 1) << 1;
  r |= ((v >> (shift + 4)) & 1) << 2;
  r |= ((v >> (shift + 6)) & 1) << 3;
  return r;
}

__device__ __forceinline__ float simpson_cell(const float* __restrict__ F,
                                              int d, int cell, float hx,
                                              float hy) {
  const int ix = compact_bits(cell, 0);
  const int iy = compact_bits(cell, 1);
  const int s = 5 - d;        // log2 of cell size in grid units
  const int h = 1 << (s - 1); // half-cell in grid units
  const int gx0 = ix << s, gx1 = gx0 + h, gx2 = gx0 + 2 * h;
  const int gy0 = iy << s, gy1 = gy0 + h, gy2 = gy0 + 2 * h;
  // point order: 0:(xl,yl) 1:(mx,yl) 2:(xr,yl) 3:(xl,my) 4:(xr,my)
  //              5:(xl,yr) 6:(mx,yr) 7:(xr,yr)   (center skipped, coeff 0)
  const float f0 = F[gy0 * GRID_N + gx0];
  const float f1 = F[gy0 * GRID_N + gx1];
  const float f2 = F[gy0 * GRID_N + gx2];
  const float f3 = F[gy1 * GRID_N + gx0];
  const float f4 = F[gy1 * GRID_N + gx2];
  const float f5 = F[gy2 * GRID_N + gx0];
  const float f6 = F[gy2 * GRID_N + gx1];
  const float f7 = F[gy2 * GRID_N + gx2];
  return hx * hy * (1.0f / 12.0f) *
         (-(f0 + f2 + f5 + f7) + 4.0f * (f1 + f3 + f4 + f6));
}

__global__ __launch_bounds__(512) void combine_kernel(
    const float* __restrict__ Fpart, const float* __restrict__ xa_p,
    const float* __restrict__ xb_p, const float* __restrict__ ya_p,
    const float* __restrict__ yb_p, const float* __restrict__ eps_p,
    float* __restrict__ out) {
  __shared__ alignas(16) float Fs[FP_STRIDE];
  __shared__ float S4[256], S3[64], S2[16], S1[4], S0[1];
  __shared__ float val3[64], val2[16], val1[4];
  const int t = threadIdx.x;
  const float xa = *xa_p, xb = *xb_p, ya = *ya_p, yb = *yb_p, eps = *eps_p;
  const float HX = fabsf(xb - xa), HY = fabsf(yb - ya);

  // --- sum split-K partials into LDS: 8 independent float4 loads/thread ---
  if (t < FP_GROUPS) {
    const float4* Fp4 = (const float4*)Fpart;  // FP_GROUPS groups per split
    float4 s = make_float4(0.0f, 0.0f, 0.0f, 0.0f);
#pragma unroll
    for (int sp = 0; sp < SPLITK; ++sp) {
      float4 v = Fp4[sp * FP_GROUPS + t];
      s.x += v.x; s.y += v.y; s.z += v.z; s.w += v.w;
    }
    ((float4*)Fs)[t] = s;  // pad lanes (p>=1089) hold garbage; never read
  }
  __syncthreads();

  // --- Simpson estimates at every depth ---
  if (t < 256) {
    S4[t] = simpson_cell(Fs, 4, t, HX * 0.0625f, HY * 0.0625f);
    if (t < 64) {
      S3[t] = simpson_cell(Fs, 3, t, HX * 0.125f, HY * 0.125f);
    } else if (t < 80) {
      S2[t - 64] = simpson_cell(Fs, 2, t - 64, HX * 0.25f, HY * 0.25f);
    } else if (t < 84) {
      S1[t - 80] = simpson_cell(Fs, 1, t - 80, HX * 0.5f, HY * 0.5f);
    } else if (t == 84) {
      S0[0] = simpson_cell(Fs, 0, 0, HX, HY);
    }
  }
  __syncthreads();

  // --- d = 3 (MAX_DEPTH-1): truncate -> corrected unconditionally ---
  if (t < 64) {
    float sumq = ((S4[4 * t] + S4[4 * t + 1]) + S4[4 * t + 2]) + S4[4 * t + 3];
    // reference bug reproduced: quadrant 3 'whole' is quadrant 0's S
    float whole = ((t & 3) == 3) ? S3[t & ~3] : S3[t];
    float delta = sumq - whole;
    val3[t] = sumq + delta * (1.0f / 15.0f);
  }
  __syncthreads();

  // --- d = 2 ---
  if (t < 16) {
    float sumq = ((S3[4 * t] + S3[4 * t + 1]) + S3[4 * t + 2]) + S3[4 * t + 3];
    float whole = ((t & 3) == 3) ? S2[t & ~3] : S2[t];
    float delta = sumq - whole;
    float corrected = sumq + delta * (1.0f / 15.0f);
    float child =
        ((val3[4 * t] + val3[4 * t + 1]) + val3[4 * t + 2]) + val3[4 * t + 3];
    float eps_d = eps * (1.0f / 16.0f);  // eps / 4^2
    val2[t] = (fabsf(delta) <= 15.0f * eps_d) ? corrected : child;
  }
  __syncthreads();

  // --- d = 1 ---
  if (t < 4) {
    float sumq = ((S2[4 * t] + S2[4 * t + 1]) + S2[4 * t + 2]) + S2[4 * t + 3];
    float whole = ((t & 3) == 3) ? S1[t & ~3] : S1[t];
    float delta = sumq - whole;
    float corrected = sumq + delta * (1.0f / 15.0f);
    float child =
        ((val2[4 * t] + val2[4 * t + 1]) + val2[4 * t + 2]) + val2[4 * t + 3];
    float eps_d = eps * 0.25f;  // eps / 4^1
    val1[t] = (fabsf(delta) <= 15.0f * eps_d) ? corrected : child;
  }
  __syncthreads();

  // --- d = 0 ---
  if (t == 0) {
    float sumq = ((S1[0] + S1[1]) + S1[2]) + S1[3];
    float delta = sumq - S0[0];
    float corrected = sumq + delta * (1.0f / 15.0f);
    float child = ((val1[0] + val1[1]) + val1[2]) + val1[3];
    out[0] = (fabsf(delta) <= 15.0f * eps) ? corrected : child;
  }
}

extern "C" void kernel_launch(void* const* d_in, const int* in_sizes, int n_in,
                              void* d_out, int out_size, void* d_ws,
                              size_t ws_size, hipStream_t stream) {
  // input order: xa, xb, ya, yb, eps, w, ax, ay, phi
  const float* xa = (const float*)d_in[0];
  const float* xb = (const float*)d_in[1];
  const float* ya = (const float*)d_in[2];
  const float* yb = (const float*)d_in[3];
  const float* eps = (const float*)d_in[4];
  const float4* w4 = (const float4*)d_in[5];
  const float4* ax4 = (const float4*)d_in[6];
  const float4* ay4 = (const float4*)d_in[7];
  const float4* phi4 = (const float4*)d_in[8];
  float* out = (float*)d_out;
  float* Fpart = (float*)d_ws;  // SPLITK * FP_STRIDE floats (34944 B)

  dim3 grid(PBLOCKS, SPLITK);
  eval_grid_kernel<<<grid, 256, 0, stream>>>(w4, ax4, ay4, phi4, xa, xb, ya,
                                             yb, Fpart);
  combine_kernel<<<1, 512, 0, stream>>>(Fpart, xa, xb, ya, yb, eps, out);
}